// Round 1
// 1234.379 us; speedup vs baseline: 1.8783x; 1.8783x over previous
//
#include <hip/hip_runtime.h>
#include <cstdint>

#define BATCH 64
#define SEQ   512
#define DIM   512
#define MTOT  (BATCH*SEQ)   // 32768

// RNN decomposition: 8 column-slices x 32 batch-groups (2 rows each) = 256 wgs
// (one per CU; previous version used 128 wgs = half the chip idle).
#define CSL 8     // column slices (64 cols each)
#define GRP 32    // batch groups
#define RPG 2     // rows per group

// ---------------------------------------------------------------------------
// Kernel 0: pack W_hh [c][j] -> Wpk[jb][c] (float4 over j%4); zero tag-pairs.
// hpair must be re-zeroed EVERY launch: stale tags from a previous run
// (graph replay) would false-match targets 1..511.
// ---------------------------------------------------------------------------
__global__ __launch_bounds__(128) void pack_w(const float* __restrict__ W,
                                              float4* __restrict__ Wpk,
                                              unsigned long long* __restrict__ hpair) {
    const int c  = blockIdx.x;
    const int jb = threadIdx.x;
    const float4 v = *(const float4*)&W[(size_t)c * DIM + 4 * jb];
    Wpk[(size_t)jb * DIM + c] = v;
    // 2 slots * GRP * RPG * DIM = 65536 pairs == gridDim.x * blockDim.x
    hpair[(size_t)blockIdx.x * 128 + threadIdx.x] = 0ull;
}

// ---------------------------------------------------------------------------
// Kernel 1: fused embedding gather + input projection (NT GEMM, fp32)
// ---------------------------------------------------------------------------
__global__ __launch_bounds__(256) void embed_proj(
    const int*   __restrict__ xidx,
    const float* __restrict__ emb,
    const float* __restrict__ W_ih,
    const float* __restrict__ b_ih,
    const float* __restrict__ b_hh,
    float*       __restrict__ xp) {
    __shared__ float As[64][68];  // As[k][m]
    __shared__ float Bs[64][68];  // Bs[k][n]

    const int m0  = blockIdx.x * 64;
    const int n0  = blockIdx.y * 64;
    const int tid = threadIdx.x;

    const int lr = tid >> 4;
    const int lc = (tid & 15) << 2;

    int rows[4];
#pragma unroll
    for (int i = 0; i < 4; i++) rows[i] = xidx[m0 + lr + 16 * i];

    const int tm = (tid & 15) << 2;
    const int tn = (tid >> 4) << 2;

    float acc[4][4];
#pragma unroll
    for (int i = 0; i < 4; i++)
#pragma unroll
        for (int j = 0; j < 4; j++) acc[i][j] = 0.0f;

    for (int k0 = 0; k0 < DIM; k0 += 64) {
#pragma unroll
        for (int i = 0; i < 4; i++) {
            const int rl = lr + 16 * i;
            const float4 a = *(const float4*)&emb[(size_t)rows[i] * DIM + k0 + lc];
            As[lc + 0][rl] = a.x; As[lc + 1][rl] = a.y;
            As[lc + 2][rl] = a.z; As[lc + 3][rl] = a.w;
            const float4 b = *(const float4*)&W_ih[(size_t)(n0 + rl) * DIM + k0 + lc];
            Bs[lc + 0][rl] = b.x; Bs[lc + 1][rl] = b.y;
            Bs[lc + 2][rl] = b.z; Bs[lc + 3][rl] = b.w;
        }
        __syncthreads();
#pragma unroll 8
        for (int kk = 0; kk < 64; kk++) {
            const float4 a = *(const float4*)&As[kk][tm];
            const float4 b = *(const float4*)&Bs[kk][tn];
            acc[0][0] = fmaf(a.x, b.x, acc[0][0]);
            acc[0][1] = fmaf(a.x, b.y, acc[0][1]);
            acc[0][2] = fmaf(a.x, b.z, acc[0][2]);
            acc[0][3] = fmaf(a.x, b.w, acc[0][3]);
            acc[1][0] = fmaf(a.y, b.x, acc[1][0]);
            acc[1][1] = fmaf(a.y, b.y, acc[1][1]);
            acc[1][2] = fmaf(a.y, b.z, acc[1][2]);
            acc[1][3] = fmaf(a.y, b.w, acc[1][3]);
            acc[2][0] = fmaf(a.z, b.x, acc[2][0]);
            acc[2][1] = fmaf(a.z, b.y, acc[2][1]);
            acc[2][2] = fmaf(a.z, b.z, acc[2][2]);
            acc[2][3] = fmaf(a.z, b.w, acc[2][3]);
            acc[3][0] = fmaf(a.w, b.x, acc[3][0]);
            acc[3][1] = fmaf(a.w, b.y, acc[3][1]);
            acc[3][2] = fmaf(a.w, b.z, acc[3][2]);
            acc[3][3] = fmaf(a.w, b.w, acc[3][3]);
        }
        __syncthreads();
    }

    const int n = n0 + tn;
    const float bias0 = b_ih[n + 0] + b_hh[n + 0];
    const float bias1 = b_ih[n + 1] + b_hh[n + 1];
    const float bias2 = b_ih[n + 2] + b_hh[n + 2];
    const float bias3 = b_ih[n + 3] + b_hh[n + 3];
#pragma unroll
    for (int i = 0; i < 4; i++) {
        float4 o;
        o.x = acc[i][0] + bias0;
        o.y = acc[i][1] + bias1;
        o.z = acc[i][2] + bias2;
        o.w = acc[i][3] + bias3;
        *(float4*)&xp[(size_t)(m0 + tm + i) * DIM + n] = o;
    }
}

// ---------------------------------------------------------------------------
// Kernel 2: RNN scan, W column-split across CUs.
//  Sync redesign vs prev version: data+tag fused into ONE 64-bit word
//  (lo = h bits, hi = timestep tag), stored/loaded with relaxed agent-scope
//  atomics (sc1 -> L3 directly, no cache-maintenance ops — R5 lesson kept).
//  Consumers poll the data itself: tag match == value valid. This removes
//  the flag round-trips AND the vmcnt-drain-before-flag ordering barrier.
//  Wave ks only reads h cols [ks*64, ks*64+64) == exactly slice ks's output,
//  so each wave polls only its producer slice and needs NO barrier before
//  its FMA. One __syncthreads per step (part[] reduce), part[] double-
//  buffered to make that legal.
//  __launch_bounds__(512, 1): allow up to 512 VGPR so wreg[16] (64 VGPRs)
//  stays RESIDENT — prev build showed VGPR_Count=52, i.e. W was being
//  re-streamed from L2 every step (~128 KB/wg/step).
// ---------------------------------------------------------------------------
__global__ __launch_bounds__(512, 1)
void rnn_scan(const float4* __restrict__ Wpk, float* __restrict__ buf,
              unsigned long long* __restrict__ hpair) {
    __shared__ float hlds[RPG * DIM];            // 4 KB: h(t) rows x cols
    __shared__ float part[2 * 8 * RPG * 64];     // 8 KB: double-buffered k-partials

    const int tid   = threadIdx.x;
    const int slice = blockIdx.x / GRP;   // 0..7
    const int grp   = blockIdx.x % GRP;   // 0..31
    const int c     = tid & 63;
    const int ks    = tid >> 6;           // k-slice == wave id, 0..7
    const int b0    = grp * RPG;
    const int col0  = slice * 64;
    const int hb    = ks * 16;

    // W slice held in registers for the whole scan (64 VGPRs).
    float4 wreg[16];
#pragma unroll
    for (int i = 0; i < 16; i++)
        wreg[i] = Wpk[(size_t)(hb + i) * DIM + col0 + c];

    // Each wave zeroes exactly the h region it will read -> no init barrier.
    hlds[tid]       = 0.0f;
    hlds[DIM + tid] = 0.0f;

    const int rr = tid >> 6;   // used when tid<128
    const int cc = tid & 63;
    float xq = 0.0f;
    if (tid < 128)
        xq = buf[((size_t)(b0 + rr) * SEQ + 0) * DIM + col0 + cc];

    for (int t = 0; t < SEQ; t++) {
        if (t > 0) {
            // Wave ks polls slice-ks pairs of h(t): slot t&1, tag t.
            // Lane col index == tid (tid in [ks*64, ks*64+64)).
            unsigned long long* base =
                hpair + ((size_t)(t & 1) * GRP + grp) * (RPG * DIM);
            unsigned long long v0 = __hip_atomic_load(base + tid,
                                    __ATOMIC_RELAXED, __HIP_MEMORY_SCOPE_AGENT);
            unsigned long long v1 = __hip_atomic_load(base + DIM + tid,
                                    __ATOMIC_RELAXED, __HIP_MEMORY_SCOPE_AGENT);
            const unsigned tgt = (unsigned)t;
            while (((unsigned)(v0 >> 32) != tgt) | ((unsigned)(v1 >> 32) != tgt)) {
                __builtin_amdgcn_s_sleep(1);
                v0 = __hip_atomic_load(base + tid,
                                    __ATOMIC_RELAXED, __HIP_MEMORY_SCOPE_AGENT);
                v1 = __hip_atomic_load(base + DIM + tid,
                                    __ATOMIC_RELAXED, __HIP_MEMORY_SCOPE_AGENT);
            }
            hlds[tid]       = __uint_as_float((unsigned)v0);
            hlds[DIM + tid] = __uint_as_float((unsigned)v1);
            // no barrier: this wave reads only the region it just wrote
        }

        float p0 = 0.f, p1 = 0.f;
        const float4* h4 = (const float4*)hlds;
#pragma unroll
        for (int i = 0; i < 16; i++) {
            const float4 w  = wreg[i];
            const float4 h0 = h4[0 * 128 + hb + i];
            const float4 h1 = h4[1 * 128 + hb + i];
            p0 = fmaf(w.x, h0.x, p0); p0 = fmaf(w.y, h0.y, p0);
            p0 = fmaf(w.z, h0.z, p0); p0 = fmaf(w.w, h0.w, p0);
            p1 = fmaf(w.x, h1.x, p1); p1 = fmaf(w.y, h1.y, p1);
            p1 = fmaf(w.z, h1.z, p1); p1 = fmaf(w.w, h1.w, p1);
        }
        const int pb = (t & 1) << 10;
        part[pb + ks * 128 +  0 + c] = p0;
        part[pb + ks * 128 + 64 + c] = p1;
        __syncthreads();   // the ONLY barrier per step

        if (tid < 128) {
            float s = part[pb + tid];
#pragma unroll
            for (int k = 1; k < 8; k++) s += part[pb + k * 128 + tid];
            const float hn = tanhf(xq + s);
            if (t + 1 < SEQ) {
                // fused data+tag: single 8B atomic -> consumer sees them together
                const unsigned long long pv =
                    ((unsigned long long)(unsigned)(t + 1) << 32) |
                    (unsigned long long)__float_as_uint(hn);
                __hip_atomic_store(
                    hpair + (((size_t)((t + 1) & 1) * GRP + grp) * RPG + rr) * DIM
                          + col0 + cc,
                    pv, __ATOMIC_RELAXED, __HIP_MEMORY_SCOPE_AGENT);
            }
            buf[((size_t)(b0 + rr) * SEQ + t) * DIM + col0 + cc] = hn;
            // prefetch next xp while everyone else polls (clamped in-bounds)
            const int tn = (t + 1 < SEQ) ? (t + 1) : t;
            xq = buf[((size_t)(b0 + rr) * SEQ + tn) * DIM + col0 + cc];
        }
    }
}

// ---------------------------------------------------------------------------
// Kernel 3: softmax over H (per b,t) + transpose [B][T][H] -> out [B][H][T]
// ---------------------------------------------------------------------------
__global__ __launch_bounds__(256) void softmax_T(const float* __restrict__ hid,
                                                 float* __restrict__ out) {
    __shared__ float rowmax[64];
    __shared__ float rowinv[64];
    __shared__ float tile[64][65];

    const int b   = blockIdx.x;
    const int t0  = blockIdx.y * 64;
    const int tid = threadIdx.x;
    const float* base = hid + ((size_t)b * SEQ + t0) * DIM;

    const int r = tid >> 2;
    const int p = tid & 3;

    float m = -1e30f;
#pragma unroll 4
    for (int k = 0; k < 32; k++) {
        const float4 v = *(const float4*)&base[r * DIM + ((k * 4 + p) << 2)];
        m = fmaxf(m, fmaxf(fmaxf(v.x, v.y), fmaxf(v.z, v.w)));
    }
    m = fmaxf(m, __shfl_xor(m, 1));
    m = fmaxf(m, __shfl_xor(m, 2));

    float s = 0.0f;
#pragma unroll 4
    for (int k = 0; k < 32; k++) {
        const float4 v = *(const float4*)&base[r * DIM + ((k * 4 + p) << 2)];
        s += expf(v.x - m) + expf(v.y - m) + expf(v.z - m) + expf(v.w - m);
    }
    s += __shfl_xor(s, 1);
    s += __shfl_xor(s, 2);
    if (p == 0) {
        rowmax[r] = m;
        rowinv[r] = 1.0f / s;
    }
    __syncthreads();

    for (int hc = 0; hc < 8; hc++) {
#pragma unroll
        for (int i = 0; i < 16; i++) {
            const int lin = tid + 256 * i;
            const int rr  = lin >> 6;
            const int ccc = lin & 63;
            const float v = base[rr * DIM + hc * 64 + ccc];
            tile[ccc][rr] = expf(v - rowmax[rr]) * rowinv[rr];
        }
        __syncthreads();
#pragma unroll
        for (int i = 0; i < 16; i++) {
            const int lin = tid + 256 * i;
            const int hh  = lin >> 6;
            const int tt  = lin & 63;
            out[((size_t)b * DIM + hc * 64 + hh) * SEQ + t0 + tt] = tile[hh][tt];
        }
        __syncthreads();
    }
}

// ---------------------------------------------------------------------------
extern "C" void kernel_launch(void* const* d_in, const int* in_sizes, int n_in,
                              void* d_out, int out_size, void* d_ws, size_t ws_size,
                              hipStream_t stream) {
    const int*   x    = (const int*)  d_in[0];
    const float* emb  = (const float*)d_in[1];
    const float* W_ih = (const float*)d_in[2];
    const float* W_hh = (const float*)d_in[3];
    const float* b_ih = (const float*)d_in[4];
    const float* b_hh = (const float*)d_in[5];
    float* out = (float*)d_out;

    // 64 MB scratch: xp (then hid, in place) as [B][T][H]
    float* buf = (float*)d_ws;
    // staging inside d_out (16.7M floats); all consumed before softmax_T
    // overwrites d_out (stream-ordered):
    float4* Wpk = (float4*)out;                                   // 1M floats
    unsigned long long* hpair =
        (unsigned long long*)(out + (4 << 20));                   // 512 KB tagged pairs

    pack_w<<<dim3(DIM), 128, 0, stream>>>(W_hh, Wpk, hpair);
    embed_proj<<<dim3(MTOT / 64, DIM / 64), 256, 0, stream>>>(x, emb, W_ih, b_ih, b_hh, buf);
    rnn_scan<<<CSL * GRP, 512, 0, stream>>>(Wpk, buf, hpair);
    softmax_T<<<dim3(BATCH, SEQ / 64), 256, 0, stream>>>(buf, out);
}